// Round 7
// baseline (15569.316 us; speedup 1.0000x reference)
//
#include <hip/hip_runtime.h>
#include <cstdint>
#include <cstddef>

// ---------- constants ----------
#define MM 4096
#define NSTEP 50
#define DD 100
#define HID 512
#define K0P 128          // 101 padded to 128
#define SIGC 0.4f
#define RC 0.05f
#define NWGP 256         // persistent workgroups (1 per CU)

typedef __bf16 bf16x8 __attribute__((ext_vector_type(8)));
typedef float  f32x4  __attribute__((ext_vector_type(4)));

typedef const __attribute__((address_space(1))) void* gvp;
typedef __attribute__((address_space(3))) void* lvp;

static __device__ __forceinline__ void load_lds16(const void* g, void* l) {
    __builtin_amdgcn_global_load_lds((gvp)g, (lvp)l, 16, 0, 0);
}

// ---------- weight prep ----------
__global__ void k_transpose(const float* __restrict__ in, __bf16* __restrict__ out,
                            int Ksrc, int Kpad, int N) {
    int idx = blockIdx.x * 256 + threadIdx.x;
    if (idx >= N * Kpad) return;
    int n = idx / Kpad, k = idx - n * Kpad;
    out[idx] = (k < Ksrc) ? (__bf16)in[k * N + n] : (__bf16)0.f;
}

__global__ void k_cast(const float* __restrict__ in, __bf16* __restrict__ out,
                       int Rsrc, int Rpad, int C) {
    int idx = blockIdx.x * 256 + threadIdx.x;
    if (idx >= Rpad * C) return;
    int r = idx / C;
    out[idx] = (r < Rsrc) ? (__bf16)in[idx] : (__bf16)0.f;
}

// ---------- device-scope grid barrier (sense via monotone generation) ----------
__device__ __forceinline__ void gridbar(int* cnt, int* gen, int& g) {
    __syncthreads();
    if (threadIdx.x == 0) {
        int prev = __hip_atomic_fetch_add(cnt, 1, __ATOMIC_ACQ_REL,
                                          __HIP_MEMORY_SCOPE_AGENT);
        if (prev == NWGP - 1) {
            __hip_atomic_store(cnt, 0, __ATOMIC_RELAXED, __HIP_MEMORY_SCOPE_AGENT);
            __hip_atomic_store(gen, g + 1, __ATOMIC_RELEASE, __HIP_MEMORY_SCOPE_AGENT);
        } else {
            while (__hip_atomic_load(gen, __ATOMIC_ACQUIRE,
                                     __HIP_MEMORY_SCOPE_AGENT) < g + 1)
                __builtin_amdgcn_s_sleep(2);
        }
        g = g + 1;
    }
    __syncthreads();
}

// ---------- one GEMM phase (round-6-verified body) ----------
// BM=64, BN=128, BK=64, 4 waves (2x2), wave tile 32x64, double-buffered LDS.
// EPI 0: fwd layer: v+=bias; sin->out0, cos->out1
// EPI 1: bwd layer: v*=cmul; ->out0
// EPI 2: fwd L3: v+=bias; cos*W4->out0; Y[m] += sin*W4 (atomic)
// EPI 3: bwd L0 + Euler/terminal fused; returns resid contribution (lane0 only)
template <int EPI>
__device__ __forceinline__ float phase(
    int tid, int colBlk, int rowBlk, char* lds,
    const __bf16* __restrict__ A, const __bf16* __restrict__ Bm,
    const float* __restrict__ bias, const __bf16* __restrict__ cmul,
    __bf16* __restrict__ out0, __bf16* __restrict__ out1,
    const float* __restrict__ W4, float* __restrict__ Y,
    const float* __restrict__ t, const float* __restrict__ Wb,
    float* __restrict__ X, float* __restrict__ Ytil,
    __bf16* __restrict__ tXout, float b4v,
    int n, int K, int Nout) {

    const int wave = tid >> 6, lane = tid & 63;
    const int lr = lane & 15, lg = lane >> 4;
    const int wr = (wave >> 1) * 32;
    const int wc = (wave & 1) * 64;

    f32x4 acc4[2][4] = {};

    int aRow[2], aG[2], bRow[4], bG[4];
    #pragma unroll
    for (int it = 0; it < 2; it++) {
        int chunk = it * 256 + tid;
        aRow[it] = chunk >> 3;
        aG[it] = (chunk & 7) ^ (aRow[it] & 7);
    }
    #pragma unroll
    for (int it = 0; it < 4; it++) {
        int chunk = it * 256 + tid;
        bRow[it] = chunk >> 3;
        bG[it] = (chunk & 7) ^ (bRow[it] & 7);
    }

    const int NK = K >> 6;

    #define STAGE(kb, buf)                                                         \
        {   char* Ad_ = lds + (buf) * 8192 + wave * 1024;                          \
            char* Bd_ = lds + 16384 + (buf) * 16384 + wave * 1024;                 \
            int k0_ = (kb) << 6;                                                   \
            _Pragma("unroll")                                                      \
            for (int it = 0; it < 2; it++)                                         \
                load_lds16(A + (size_t)(rowBlk + aRow[it]) * K + k0_ + aG[it] * 8, \
                           Ad_ + it * 4096);                                       \
            _Pragma("unroll")                                                      \
            for (int it = 0; it < 4; it++)                                         \
                load_lds16(Bm + (size_t)(colBlk + bRow[it]) * K + k0_ + bG[it] * 8,\
                           Bd_ + it * 4096); }

    STAGE(0, 0)
    __syncthreads();

    for (int kb = 0; kb < NK; kb++) {
        const int cur = kb & 1;
        if (kb + 1 < NK) STAGE(kb + 1, cur ^ 1)
        const char* As = lds + cur * 8192;
        const char* Bs = lds + 16384 + cur * 16384;
        #pragma unroll
        for (int ks = 0; ks < 2; ks++) {
            bf16x8 aF[2], bF[4];
            #pragma unroll
            for (int mi = 0; mi < 2; mi++) {
                int row = wr + mi * 16 + lr;
                int p = (ks * 4 + lg) ^ (row & 7);
                aF[mi] = *(const bf16x8*)(As + row * 128 + p * 16);
            }
            #pragma unroll
            for (int nj = 0; nj < 4; nj++) {
                int row = wc + nj * 16 + lr;
                int p = (ks * 4 + lg) ^ (row & 7);
                bF[nj] = *(const bf16x8*)(Bs + row * 128 + p * 16);
            }
            #pragma unroll
            for (int mi = 0; mi < 2; mi++)
                #pragma unroll
                for (int nj = 0; nj < 4; nj++)
                    acc4[mi][nj] = __builtin_amdgcn_mfma_f32_16x16x32_bf16(
                        aF[mi], bF[nj], acc4[mi][nj], 0, 0, 0);
        }
        __syncthreads();
    }
    #undef STAGE

    if (EPI == 0) {
        #pragma unroll
        for (int nj = 0; nj < 4; nj++) {
            int col = colBlk + wc + nj * 16 + lr;
            float bv = bias[col];
            #pragma unroll
            for (int mi = 0; mi < 2; mi++)
                #pragma unroll
                for (int r = 0; r < 4; r++) {
                    int row = rowBlk + wr + mi * 16 + lg * 4 + r;
                    float v = acc4[mi][nj][r] + bv;
                    float s, c;
                    __sincosf(v, &s, &c);
                    out0[(size_t)row * Nout + col] = (__bf16)s;
                    out1[(size_t)row * Nout + col] = (__bf16)c;
                }
        }
    } else if (EPI == 1) {
        #pragma unroll
        for (int nj = 0; nj < 4; nj++) {
            int col = colBlk + wc + nj * 16 + lr;
            #pragma unroll
            for (int mi = 0; mi < 2; mi++)
                #pragma unroll
                for (int r = 0; r < 4; r++) {
                    int row = rowBlk + wr + mi * 16 + lg * 4 + r;
                    float v = acc4[mi][nj][r] * (float)cmul[(size_t)row * Nout + col];
                    out0[(size_t)row * Nout + col] = (__bf16)v;
                }
        }
    } else if (EPI == 2) {
        float ysum[2][4] = {};
        #pragma unroll
        for (int nj = 0; nj < 4; nj++) {
            int col = colBlk + wc + nj * 16 + lr;
            float bv = bias[col];
            float w4 = W4[col];
            #pragma unroll
            for (int mi = 0; mi < 2; mi++)
                #pragma unroll
                for (int r = 0; r < 4; r++) {
                    int row = rowBlk + wr + mi * 16 + lg * 4 + r;
                    float v = acc4[mi][nj][r] + bv;
                    float s, c;
                    __sincosf(v, &s, &c);
                    out0[(size_t)row * Nout + col] = (__bf16)(c * w4);
                    ysum[mi][r] += s * w4;
                }
        }
        #pragma unroll
        for (int mi = 0; mi < 2; mi++)
            #pragma unroll
            for (int r = 0; r < 4; r++) {
                float v = ysum[mi][r];
                v += __shfl_xor(v, 1);
                v += __shfl_xor(v, 2);
                v += __shfl_xor(v, 4);
                v += __shfl_xor(v, 8);
                if (lr == 0) {
                    int row = rowBlk + wr + mi * 16 + lg * 4 + r;
                    atomicAdd(&Y[row], v);
                }
            }
    } else {  // EPI == 3
        __syncthreads();
        float* Zs = (float*)lds;   // [64][132] f32
        #pragma unroll
        for (int nj = 0; nj < 4; nj++) {
            int col = wc + nj * 16 + lr;
            #pragma unroll
            for (int mi = 0; mi < 2; mi++)
                #pragma unroll
                for (int r = 0; r < 4; r++) {
                    int rl = wr + mi * 16 + lg * 4 + r;
                    Zs[rl * 132 + col] = acc4[mi][nj][r];
                }
        }
        __syncthreads();
        float resid = 0.f;
        for (int rl = 0; rl < 16; rl++) {
            int lrow = wave * 16 + rl;
            int grow = rowBlk + lrow;
            float t0v = 0.f, t1v = 0.f;
            if (n < NSTEP) {
                t0v = t[grow * (NSTEP + 1) + n];
                t1v = t[grow * (NSTEP + 1) + n + 1];
            }
            float pXZ = 0.f, pZs = 0.f, gX = 0.f, sD = 0.f;
            #pragma unroll
            for (int ii = 0; ii < 2; ii++) {
                int d = lane + ii * 64;
                if (d < DD) {
                    float x0 = X[grow * DD + d];
                    float z = Zs[lrow * 132 + 1 + d];
                    if (n < NSTEP) {
                        float dWv = Wb[((size_t)grow * (NSTEP + 1) + n + 1) * DD + d] -
                                    Wb[((size_t)grow * (NSTEP + 1) + n) * DD + d];
                        float s = SIGC * x0 * dWv;
                        pXZ += x0 * z;
                        pZs += z * s;
                        float x1 = x0 + s;
                        X[grow * DD + d] = x1;
                        tXout[(size_t)grow * K0P + 1 + d] = (__bf16)x1;
                    } else {
                        gX += x0 * x0;
                        float e = z - 2.f * x0;
                        sD += e * e;
                    }
                }
            }
            for (int off = 32; off; off >>= 1) {
                pXZ += __shfl_down(pXZ, off);
                pZs += __shfl_down(pZs, off);
                gX  += __shfl_down(gX, off);
                sD  += __shfl_down(sD, off);
            }
            if (lane == 0) {
                float y0 = Y[grow];
                if (n >= 1) {
                    float dd = y0 - Ytil[grow];
                    resid += dd * dd;
                }
                if (n < NSTEP) {
                    float phi = RC * (y0 - pXZ);
                    Ytil[grow] = y0 + phi * (t1v - t0v) + pZs;
                    tXout[(size_t)grow * K0P] = (__bf16)t1v;
                    Y[grow] = b4v;
                } else {
                    float e = y0 - gX;
                    resid += e * e + sD;
                }
            }
        }
        return resid;   // nonzero only on lane==0 threads
    }
    return 0.f;
}

// ---------- persistent megakernel ----------
__global__ __launch_bounds__(256, 1) void mega(
    const float* __restrict__ t, const float* __restrict__ W,
    const float* __restrict__ Xi,
    const __bf16* __restrict__ wt0, const __bf16* __restrict__ wt1,
    const __bf16* __restrict__ wt2, const __bf16* __restrict__ wt3,
    const __bf16* __restrict__ wd0, const __bf16* __restrict__ wd1,
    const __bf16* __restrict__ wd2, const __bf16* __restrict__ wd3,
    const float* __restrict__ b0, const float* __restrict__ b1,
    const float* __restrict__ b2, const float* __restrict__ b3,
    const float* __restrict__ W4, const float* __restrict__ b4,
    __bf16* __restrict__ tX,
    __bf16* __restrict__ a0, __bf16* __restrict__ a1, __bf16* __restrict__ a2,
    __bf16* __restrict__ c0, __bf16* __restrict__ c1, __bf16* __restrict__ c2,
    __bf16* __restrict__ gza, __bf16* __restrict__ gzb,
    float* __restrict__ X, float* __restrict__ Y, float* __restrict__ Ytil,
    float* __restrict__ acc, int* cnt, int* gen) {

    __shared__ __align__(16) char lds[49152];
    const int tid = threadIdx.x;
    const int wg = blockIdx.x;
    const int colBlk = (wg & 3) * 128;
    const int rowBlk = (wg >> 2) * 64;
    int g = 0;
    const float b4v = b4[0];

    // ---- init: this WG owns rows [wg*16, wg*16+16) ----
    {
        int row = wg * 16 + (tid >> 4);
        int c8 = (tid & 15) * 8;
        #pragma unroll
        for (int i = 0; i < 8; i++) {
            int col = c8 + i;
            float v;
            if (col == 0) v = t[row * (NSTEP + 1)];
            else if (col <= DD) v = Xi[col - 1];
            else v = 0.f;
            tX[(size_t)row * K0P + col] = (__bf16)v;
            if (col >= 1 && col <= DD) X[row * DD + col - 1] = v;
        }
        if ((tid & 15) == 0) Y[row] = b4v;
    }
    float resid = 0.f;
    gridbar(cnt, gen, g);

    for (int n = 0; n <= NSTEP; n++) {
        phase<0>(tid, colBlk, rowBlk, lds, tX, wt0, b0, nullptr, a0, c0,
                 nullptr, nullptr, nullptr, nullptr, nullptr, nullptr, nullptr,
                 0.f, n, K0P, HID);
        gridbar(cnt, gen, g);
        phase<0>(tid, colBlk, rowBlk, lds, a0, wt1, b1, nullptr, a1, c1,
                 nullptr, nullptr, nullptr, nullptr, nullptr, nullptr, nullptr,
                 0.f, n, HID, HID);
        gridbar(cnt, gen, g);
        phase<0>(tid, colBlk, rowBlk, lds, a1, wt2, b2, nullptr, a2, c2,
                 nullptr, nullptr, nullptr, nullptr, nullptr, nullptr, nullptr,
                 0.f, n, HID, HID);
        gridbar(cnt, gen, g);
        phase<2>(tid, colBlk, rowBlk, lds, a2, wt3, b3, nullptr, gza, nullptr,
                 W4, Y, nullptr, nullptr, nullptr, nullptr, nullptr,
                 0.f, n, HID, HID);
        gridbar(cnt, gen, g);
        phase<1>(tid, colBlk, rowBlk, lds, gza, wd3, nullptr, c2, gzb, nullptr,
                 nullptr, nullptr, nullptr, nullptr, nullptr, nullptr, nullptr,
                 0.f, n, HID, HID);
        gridbar(cnt, gen, g);
        phase<1>(tid, colBlk, rowBlk, lds, gzb, wd2, nullptr, c1, gza, nullptr,
                 nullptr, nullptr, nullptr, nullptr, nullptr, nullptr, nullptr,
                 0.f, n, HID, HID);
        gridbar(cnt, gen, g);
        phase<1>(tid, colBlk, rowBlk, lds, gza, wd1, nullptr, c0, gzb, nullptr,
                 nullptr, nullptr, nullptr, nullptr, nullptr, nullptr, nullptr,
                 0.f, n, HID, HID);
        gridbar(cnt, gen, g);
        if ((wg & 3) == 0)
            resid += phase<3>(tid, 0, rowBlk, lds, gzb, wd0, nullptr, nullptr,
                              nullptr, nullptr, nullptr, Y, t, W, X, Ytil, tX,
                              b4v, n, HID, K0P);
        gridbar(cnt, gen, g);
    }

    if ((wg & 3) == 0 && (tid & 63) == 0) atomicAdd(acc, resid);
}

__global__ void k_final(const float* __restrict__ acc, float* __restrict__ out) {
    out[0] = acc[0] / (float)MM;
}

// ---------- host ----------
extern "C" void kernel_launch(void* const* d_in, const int* in_sizes, int n_in,
                              void* d_out, int out_size, void* d_ws, size_t ws_size,
                              hipStream_t stream) {
    (void)in_sizes; (void)n_in; (void)out_size; (void)ws_size;
    const float* t  = (const float*)d_in[0];
    const float* W  = (const float*)d_in[1];
    const float* Xi = (const float*)d_in[2];
    const float* Wm[5];
    const float* bb[5];
    for (int i = 0; i < 5; i++) {
        Wm[i] = (const float*)d_in[3 + 2 * i];
        bb[i] = (const float*)d_in[4 + 2 * i];
    }

    char* p = (char*)d_ws;
    auto alloc = [&](size_t bytes) -> void* {
        void* r = (void*)p;
        p += (bytes + 255) & ~(size_t)255;
        return r;
    };

    __bf16* wt[4];
    wt[0] = (__bf16*)alloc((size_t)HID * K0P * 2);
    for (int i = 1; i < 4; i++) wt[i] = (__bf16*)alloc((size_t)HID * HID * 2);
    __bf16* wd[4];
    wd[0] = (__bf16*)alloc((size_t)K0P * HID * 2);
    for (int i = 1; i < 4; i++) wd[i] = (__bf16*)alloc((size_t)HID * HID * 2);
    __bf16* tX = (__bf16*)alloc((size_t)MM * K0P * 2);
    __bf16 *a[3], *c[3];
    for (int i = 0; i < 3; i++) a[i] = (__bf16*)alloc((size_t)MM * HID * 2);
    for (int i = 0; i < 3; i++) c[i] = (__bf16*)alloc((size_t)MM * HID * 2);
    __bf16* gza = (__bf16*)alloc((size_t)MM * HID * 2);
    __bf16* gzb = (__bf16*)alloc((size_t)MM * HID * 2);
    float* X    = (float*)alloc((size_t)MM * DD * 4);
    float* Y    = (float*)alloc((size_t)MM * 4);
    float* Ytil = (float*)alloc((size_t)MM * 4);
    float* acc  = (float*)alloc(256);
    int*   barr = (int*)alloc(256);

    hipMemsetAsync(acc, 0, 256, stream);
    hipMemsetAsync(barr, 0, 256, stream);

    // weight prep
    k_transpose<<<(HID * K0P + 255) / 256, 256, 0, stream>>>(Wm[0], wt[0], 101, K0P, HID);
    for (int i = 1; i < 4; i++)
        k_transpose<<<(HID * HID + 255) / 256, 256, 0, stream>>>(Wm[i], wt[i], HID, HID, HID);
    k_cast<<<(K0P * HID + 255) / 256, 256, 0, stream>>>(Wm[0], wd[0], 101, K0P, HID);
    for (int i = 1; i < 4; i++)
        k_cast<<<(HID * HID + 255) / 256, 256, 0, stream>>>(Wm[i], wd[i], HID, HID, HID);

    int* cnt = barr;        // offset 0
    int* gen = barr + 32;   // offset 128 B

    mega<<<dim3(NWGP), dim3(256), 0, stream>>>(
        t, W, Xi,
        wt[0], wt[1], wt[2], wt[3],
        wd[0], wd[1], wd[2], wd[3],
        bb[0], bb[1], bb[2], bb[3],
        Wm[4], bb[4],
        tX, a[0], a[1], a[2], c[0], c[1], c[2], gza, gzb,
        X, Y, Ytil, acc, cnt, gen);

    k_final<<<1, 1, 0, stream>>>(acc, (float*)d_out);
}